// Round 2
// baseline (1957.387 us; speedup 1.0000x reference)
//
#include <hip/hip_runtime.h>

#define N_NODES 100000
#define IN_CH 512
#define HID_CH 256
#define OUT_CH 32
#define K_STEPS 10
#define ALPHA 0.1f
#define BK 32

// ---------------- CSR build ----------------

__global__ void zero_kernel(int* __restrict__ p, int n) {
    int i = blockIdx.x * 256 + threadIdx.x;
    if (i < n) p[i] = 0;
}

__global__ void hist_kernel(const int* __restrict__ ei, int* __restrict__ cnt, int E) {
    int e = blockIdx.x * 256 + threadIdx.x;
    if (e < E) atomicAdd(&cnt[ei[E + e]], 1);
}

// per-chunk (1024 elems) exclusive scan; writes chunk sums
__global__ void scan1_kernel(const int* __restrict__ cnt, int* __restrict__ row_ptr,
                             int* __restrict__ sums, int n) {
    __shared__ int sh[256];
    int tid = threadIdx.x;
    int base = blockIdx.x * 1024 + tid * 4;
    int v0 = 0, v1 = 0, v2 = 0, v3 = 0;
    if (base + 0 < n) v0 = cnt[base + 0];
    if (base + 1 < n) v1 = cnt[base + 1];
    if (base + 2 < n) v2 = cnt[base + 2];
    if (base + 3 < n) v3 = cnt[base + 3];
    int s = v0 + v1 + v2 + v3;
    sh[tid] = s;
    __syncthreads();
    for (int off = 1; off < 256; off <<= 1) {
        int t = (tid >= off) ? sh[tid - off] : 0;
        __syncthreads();
        sh[tid] += t;
        __syncthreads();
    }
    int excl = sh[tid] - s;
    if (tid == 255) sums[blockIdx.x] = sh[tid];
    int run = excl;
    if (base + 0 < n) { row_ptr[base + 0] = run; run += v0; }
    if (base + 1 < n) { row_ptr[base + 1] = run; run += v1; }
    if (base + 2 < n) { row_ptr[base + 2] = run; run += v2; }
    if (base + 3 < n) { row_ptr[base + 3] = run; run += v3; }
}

__global__ void scan2_kernel(const int* __restrict__ sums, int* __restrict__ chunk_off, int nchunks) {
    __shared__ int sh[128];
    int tid = threadIdx.x;
    int v = (tid < nchunks) ? sums[tid] : 0;
    sh[tid] = v;
    __syncthreads();
    for (int off = 1; off < 128; off <<= 1) {
        int t = (tid >= off) ? sh[tid - off] : 0;
        __syncthreads();
        sh[tid] += t;
        __syncthreads();
    }
    chunk_off[tid] = sh[tid] - v;  // exclusive
}

__global__ void scan3_kernel(const int* __restrict__ cnt, const int* __restrict__ chunk_off,
                             int* __restrict__ row_ptr, int* __restrict__ fill,
                             float* __restrict__ dinv, int n, int E) {
    int i = blockIdx.x * 256 + threadIdx.x;
    if (i < n) {
        int ro = row_ptr[i] + chunk_off[i >> 10];
        row_ptr[i] = ro;
        fill[i] = ro;
        dinv[i] = rsqrtf((float)(cnt[i] + 1));  // +1 self-loop
    }
    if (i == 0) row_ptr[n] = E;
}

__global__ void scatter_kernel(const int* __restrict__ ei, int* __restrict__ fill,
                               int* __restrict__ col, int E) {
    int e = blockIdx.x * 256 + threadIdx.x;
    if (e < E) {
        int s = ei[e];
        int d = ei[E + e];
        int pos = atomicAdd(&fill[d], 1);
        col[pos] = s;
    }
}

// ---------------- fused MLP: h0 = relu(x@W1+b1)@W2+b2 ; g0 = dinv*h0 ----------------
// block = 256 threads, 32 rows/block; GEMM1 BK=32 w/ transposed-A LDS;
// GEMM2 via LDS hid tile. {Ast,Bs} union W2s -> 68KB LDS, 2 blocks/CU.

__global__ __launch_bounds__(256) void mlp_kernel(
    const float* __restrict__ x, const float* __restrict__ W1, const float* __restrict__ b1,
    const float* __restrict__ W2, const float* __restrict__ b2, const float* __restrict__ dinv,
    float* __restrict__ h0p, float* __restrict__ g0p) {
    __shared__ union {
        struct { float Ast[BK][32]; float Bs[BK][256]; } p1;  // 4KB + 32KB
        float W2s[HID_CH * OUT_CH];                           // 32KB
    } u;
    __shared__ float hs[32][256];                             // 32KB

    const int tid = threadIdx.x;
    const int tr = tid >> 5, tc = tid & 31;  // thread rows tr*4+[0..3], cols tc*4+j & 128+tc*4+j
    const int row0 = blockIdx.x * 32;

    float acc[4][8];
#pragma unroll
    for (int i = 0; i < 4; i++)
#pragma unroll
        for (int j = 0; j < 8; j++) acc[i][j] = 0.f;

    const int ar = tid >> 3;        // 0..31 (row within tile)
    const int ak4 = (tid & 7) * 4;  // 0,4,..,28 (k within BK)

    for (int k0 = 0; k0 < IN_CH; k0 += BK) {
        // A: 32 rows x 32 k, float4 per thread, coalesced 128B per row-chunk
        float4 a4 = *(const float4*)&x[(size_t)(row0 + ar) * IN_CH + k0 + ak4];
        u.p1.Ast[ak4 + 0][ar] = a4.x;
        u.p1.Ast[ak4 + 1][ar] = a4.y;
        u.p1.Ast[ak4 + 2][ar] = a4.z;
        u.p1.Ast[ak4 + 3][ar] = a4.w;
        // B: 32 k x 256 n, 8 float4 per thread, fully coalesced
#pragma unroll
        for (int q = 0; q < 8; q++) {
            int idx = q * 256 + tid;  // float4 index in 32x64 grid
            int brow = idx >> 6;
            int bc4 = (idx & 63) * 4;
            *(float4*)&u.p1.Bs[brow][bc4] =
                *(const float4*)&W1[(size_t)(k0 + brow) * HID_CH + bc4];
        }
        __syncthreads();
#pragma unroll
        for (int kk = 0; kk < BK; kk++) {
            float4 av = *(const float4*)&u.p1.Ast[kk][tr * 4];
            float4 b0 = *(const float4*)&u.p1.Bs[kk][tc * 4];
            float4 b1v = *(const float4*)&u.p1.Bs[kk][128 + tc * 4];
            float a[4] = {av.x, av.y, av.z, av.w};
#pragma unroll
            for (int i = 0; i < 4; i++) {
                acc[i][0] = fmaf(a[i], b0.x, acc[i][0]);
                acc[i][1] = fmaf(a[i], b0.y, acc[i][1]);
                acc[i][2] = fmaf(a[i], b0.z, acc[i][2]);
                acc[i][3] = fmaf(a[i], b0.w, acc[i][3]);
                acc[i][4] = fmaf(a[i], b1v.x, acc[i][4]);
                acc[i][5] = fmaf(a[i], b1v.y, acc[i][5]);
                acc[i][6] = fmaf(a[i], b1v.z, acc[i][6]);
                acc[i][7] = fmaf(a[i], b1v.w, acc[i][7]);
            }
        }
        __syncthreads();
    }

    // bias + relu -> hid tile in LDS (vectorized stores)
    {
        float4 bb0 = *(const float4*)&b1[tc * 4];
        float4 bb1 = *(const float4*)&b1[128 + tc * 4];
#pragma unroll
        for (int i = 0; i < 4; i++) {
            float4 v0, v1;
            v0.x = fmaxf(acc[i][0] + bb0.x, 0.f);
            v0.y = fmaxf(acc[i][1] + bb0.y, 0.f);
            v0.z = fmaxf(acc[i][2] + bb0.z, 0.f);
            v0.w = fmaxf(acc[i][3] + bb0.w, 0.f);
            v1.x = fmaxf(acc[i][4] + bb1.x, 0.f);
            v1.y = fmaxf(acc[i][5] + bb1.y, 0.f);
            v1.z = fmaxf(acc[i][6] + bb1.z, 0.f);
            v1.w = fmaxf(acc[i][7] + bb1.w, 0.f);
            *(float4*)&hs[tr * 4 + i][tc * 4] = v0;
            *(float4*)&hs[tr * 4 + i][128 + tc * 4] = v1;
        }
    }

    // stage W2 into LDS (overwrites Ast/Bs; safe: last compute sync passed)
    {
        float4* d4 = (float4*)u.W2s;
        const float4* s4 = (const float4*)W2;
#pragma unroll
        for (int q = 0; q < 8; q++) d4[q * 256 + tid] = s4[q * 256 + tid];
    }
    __syncthreads();

    // GEMM2: 32x32 outputs; thread -> rows rg*4+[0..3], col o
    const int rg = tid >> 5, o = tid & 31;
    float o0 = 0.f, o1 = 0.f, o2 = 0.f, o3 = 0.f;
    for (int c = 0; c < HID_CH; c += 4) {
        float4 h0v = *(const float4*)&hs[rg * 4 + 0][c];
        float4 h1v = *(const float4*)&hs[rg * 4 + 1][c];
        float4 h2v = *(const float4*)&hs[rg * 4 + 2][c];
        float4 h3v = *(const float4*)&hs[rg * 4 + 3][c];
        float w0 = u.W2s[(c + 0) * OUT_CH + o];
        float w1 = u.W2s[(c + 1) * OUT_CH + o];
        float w2 = u.W2s[(c + 2) * OUT_CH + o];
        float w3 = u.W2s[(c + 3) * OUT_CH + o];
        o0 = fmaf(h0v.x, w0, fmaf(h0v.y, w1, fmaf(h0v.z, w2, fmaf(h0v.w, w3, o0))));
        o1 = fmaf(h1v.x, w0, fmaf(h1v.y, w1, fmaf(h1v.z, w2, fmaf(h1v.w, w3, o1))));
        o2 = fmaf(h2v.x, w0, fmaf(h2v.y, w1, fmaf(h2v.z, w2, fmaf(h2v.w, w3, o2))));
        o3 = fmaf(h3v.x, w0, fmaf(h3v.y, w1, fmaf(h3v.z, w2, fmaf(h3v.w, w3, o3))));
    }
    float bb = b2[o];
    float vals[4] = {o0, o1, o2, o3};
#pragma unroll
    for (int i = 0; i < 4; i++) {
        int r = row0 + rg * 4 + i;
        float v = vals[i] + bb;
        h0p[(size_t)r * OUT_CH + o] = v;
        g0p[(size_t)r * OUT_CH + o] = dinv[r] * v;
    }
}

// ---------------- propagation step (pull, no atomics) ----------------
// state iterated on g = dinv*h ; h materialized only on the final step.
// h' = alpha*h0 + (1-alpha)*dinv*(sum_{in-edges} g[src] + g[v]) ; g' = dinv*h'

__global__ __launch_bounds__(256) void prop_kernel(
    const float* __restrict__ g_in, const float* __restrict__ h0,
    const float* __restrict__ dinv, const int* __restrict__ row_ptr,
    const int* __restrict__ col, float* __restrict__ out, int final_step) {
    int v = blockIdx.x * 8 + threadIdx.y;
    if (v >= N_NODES) return;
    int c = threadIdx.x;
    int beg = row_ptr[v], end = row_ptr[v + 1];
    float acc = 0.f;
    int j = beg;
    for (; j + 3 < end; j += 4) {
        int s0 = col[j], s1 = col[j + 1], s2 = col[j + 2], s3 = col[j + 3];
        float a = g_in[(size_t)s0 * OUT_CH + c];
        float b = g_in[(size_t)s1 * OUT_CH + c];
        float d = g_in[(size_t)s2 * OUT_CH + c];
        float e = g_in[(size_t)s3 * OUT_CH + c];
        acc += (a + b) + (d + e);
    }
    for (; j < end; ++j) acc += g_in[(size_t)col[j] * OUT_CH + c];
    acc += g_in[(size_t)v * OUT_CH + c];  // self-loop: g[v]
    float dv = dinv[v];
    float h = ALPHA * h0[(size_t)v * OUT_CH + c] + (1.f - ALPHA) * dv * acc;
    out[(size_t)v * OUT_CH + c] = final_step ? h : dv * h;
}

// ---------------- launch ----------------

extern "C" void kernel_launch(void* const* d_in, const int* in_sizes, int n_in,
                              void* d_out, int out_size, void* d_ws, size_t ws_size,
                              hipStream_t stream) {
    const float* x = (const float*)d_in[0];
    const int* ei = (const int*)d_in[1];  // harness stages integers as int32
    const float* W1 = (const float*)d_in[2];
    const float* b1 = (const float*)d_in[3];
    const float* W2 = (const float*)d_in[4];
    const float* b2 = (const float*)d_in[5];
    float* out = (float*)d_out;
    const int E = in_sizes[1] / 2;

    char* ws = (char*)d_ws;
    size_t off = 0;
    auto alloc = [&](size_t bytes) -> void* {
        void* p = ws + off;
        off = (off + bytes + 255) & ~(size_t)255;
        return p;
    };
    int* cnt = (int*)alloc((size_t)N_NODES * 4);
    int* row_ptr = (int*)alloc((size_t)(N_NODES + 1) * 4);
    int* fill = (int*)alloc((size_t)N_NODES * 4);
    float* dinv = (float*)alloc((size_t)N_NODES * 4);
    int* sums = (int*)alloc(128 * 4);
    int* chunk_off = (int*)alloc(128 * 4);
    int* col = (int*)alloc((size_t)E * 4);
    float* h0 = (float*)alloc((size_t)N_NODES * OUT_CH * 4);
    float* g0 = (float*)alloc((size_t)N_NODES * OUT_CH * 4);
    float* gA = (float*)alloc((size_t)N_NODES * OUT_CH * 4);

    const int nchunks = (N_NODES + 1023) / 1024;  // 98

    zero_kernel<<<(N_NODES + 255) / 256, 256, 0, stream>>>(cnt, N_NODES);
    hist_kernel<<<(E + 255) / 256, 256, 0, stream>>>(ei, cnt, E);
    scan1_kernel<<<nchunks, 256, 0, stream>>>(cnt, row_ptr, sums, N_NODES);
    scan2_kernel<<<1, 128, 0, stream>>>(sums, chunk_off, nchunks);
    scan3_kernel<<<(N_NODES + 255) / 256, 256, 0, stream>>>(cnt, chunk_off, row_ptr, fill, dinv,
                                                            N_NODES, E);
    scatter_kernel<<<(E + 255) / 256, 256, 0, stream>>>(ei, fill, col, E);

    mlp_kernel<<<N_NODES / 32, 256, 0, stream>>>(x, W1, b1, W2, b2, dinv, h0, g0);

    dim3 pb(32, 8);
    int pg = (N_NODES + 7) / 8;
    const float* gin = g0;
    float* gout = gA;
    for (int s = 0; s < K_STEPS; s++) {
        int fin = (s == K_STEPS - 1);
        float* o = fin ? out : gout;
        prop_kernel<<<pg, pb, 0, stream>>>(gin, h0, dinv, row_ptr, col, o, fin);
        if (!fin) {
            float* t = (float*)gin;
            gin = gout;
            gout = (t == g0) ? g0 : gA;  // swap: write target alternates g0/gA
            gout = t;
        }
    }
}

// Round 3
// 1345.190 us; speedup vs baseline: 1.4551x; 1.4551x over previous
//
#include <hip/hip_runtime.h>

#define N_NODES 100000
#define IN_CH 512
#define HID_CH 256
#define OUT_CH 32
#define K_STEPS 10
#define ALPHA 0.1f
#define BK 16

// ---------------- CSR build ----------------

__global__ void zero_kernel(int* __restrict__ p, int n) {
    int i = blockIdx.x * 256 + threadIdx.x;
    if (i < n) p[i] = 0;
}

__global__ void hist_kernel(const int* __restrict__ ei, int* __restrict__ cnt, int E) {
    int e = blockIdx.x * 256 + threadIdx.x;
    if (e < E) atomicAdd(&cnt[ei[E + e]], 1);
}

// per-chunk (1024 elems) exclusive scan; writes chunk sums
__global__ void scan1_kernel(const int* __restrict__ cnt, int* __restrict__ row_ptr,
                             int* __restrict__ sums, int n) {
    __shared__ int sh[256];
    int tid = threadIdx.x;
    int base = blockIdx.x * 1024 + tid * 4;
    int v0 = 0, v1 = 0, v2 = 0, v3 = 0;
    if (base + 0 < n) v0 = cnt[base + 0];
    if (base + 1 < n) v1 = cnt[base + 1];
    if (base + 2 < n) v2 = cnt[base + 2];
    if (base + 3 < n) v3 = cnt[base + 3];
    int s = v0 + v1 + v2 + v3;
    sh[tid] = s;
    __syncthreads();
    for (int off = 1; off < 256; off <<= 1) {
        int t = (tid >= off) ? sh[tid - off] : 0;
        __syncthreads();
        sh[tid] += t;
        __syncthreads();
    }
    int excl = sh[tid] - s;
    if (tid == 255) sums[blockIdx.x] = sh[tid];
    int run = excl;
    if (base + 0 < n) { row_ptr[base + 0] = run; run += v0; }
    if (base + 1 < n) { row_ptr[base + 1] = run; run += v1; }
    if (base + 2 < n) { row_ptr[base + 2] = run; run += v2; }
    if (base + 3 < n) { row_ptr[base + 3] = run; run += v3; }
}

__global__ void scan2_kernel(const int* __restrict__ sums, int* __restrict__ chunk_off, int nchunks) {
    __shared__ int sh[128];
    int tid = threadIdx.x;
    int v = (tid < nchunks) ? sums[tid] : 0;
    sh[tid] = v;
    __syncthreads();
    for (int off = 1; off < 128; off <<= 1) {
        int t = (tid >= off) ? sh[tid - off] : 0;
        __syncthreads();
        sh[tid] += t;
        __syncthreads();
    }
    chunk_off[tid] = sh[tid] - v;  // exclusive
}

__global__ void scan3_kernel(const int* __restrict__ cnt, const int* __restrict__ chunk_off,
                             int* __restrict__ row_ptr, int* __restrict__ fill,
                             float* __restrict__ dinv, int n, int E) {
    int i = blockIdx.x * 256 + threadIdx.x;
    if (i < n) {
        int ro = row_ptr[i] + chunk_off[i >> 10];
        row_ptr[i] = ro;
        fill[i] = ro;
        dinv[i] = rsqrtf((float)(cnt[i] + 1));  // +1 self-loop
    }
    if (i == 0) row_ptr[n] = E;
}

__global__ void scatter_kernel(const int* __restrict__ ei, int* __restrict__ fill,
                               int* __restrict__ col, int E) {
    int e = blockIdx.x * 256 + threadIdx.x;
    if (e < E) {
        int s = ei[e];
        int d = ei[E + e];
        int pos = atomicAdd(&fill[d], 1);
        col[pos] = s;
    }
}

// ---------------- fused MLP: h0 = relu(x@W1+b1)@W2+b2 ; g0 = dinv*h0 ----------------
// 256 threads, 32 rows x 256 cols per block. All hot LDS reads are
// 2-way-or-less (free) or broadcast:
//   A: Ast[BK][36] padded, b128 broadcast reads (2 addrs/wave)
//   B: per-thread cols tc*2+64j+{0,1} -> ds_read_b64 at addr 2*tc (2 lanes/bank)
// GEMM2 reads hs broadcast + W2 from global (L1-resident). LDS 50.5KB -> 3 blocks/CU.

__global__ __launch_bounds__(256) void mlp_kernel(
    const float* __restrict__ x, const float* __restrict__ W1, const float* __restrict__ b1,
    const float* __restrict__ W2, const float* __restrict__ b2, const float* __restrict__ dinv,
    float* __restrict__ h0p, float* __restrict__ g0p) {
    __shared__ float Ast[BK][36];    // padded: stores <=2-way, reads 16B-aligned
    __shared__ float Bs[BK][256];    // 16KB
    __shared__ float hs[32][256];    // 32KB

    const int tid = threadIdx.x;
    const int tr = tid >> 5;   // 0..7 -> rows tr*4+i
    const int tc = tid & 31;   // cols tc*2 + 64*j + {0,1}
    const int row0 = blockIdx.x * 32;

    float acc[4][8];
#pragma unroll
    for (int i = 0; i < 4; i++)
#pragma unroll
        for (int j = 0; j < 8; j++) acc[i][j] = 0.f;

    const int ar = tid >> 3;        // 0..31 row in tile
    const int ak = (tid & 7) * 2;   // k pair within BK

    for (int k0 = 0; k0 < IN_CH; k0 += BK) {
        // stage A (32 rows x 16 k), transposed, float2 per thread
        float2 a2 = *(const float2*)&x[(size_t)(row0 + ar) * IN_CH + k0 + ak];
        Ast[ak][ar] = a2.x;
        Ast[ak + 1][ar] = a2.y;
        // stage B (16 k x 256 n), 4 float4 per thread, contiguous
#pragma unroll
        for (int q = 0; q < 4; q++) {
            int idx = q * 256 + tid;
            int br = idx >> 6;
            int bc = (idx & 63) * 4;
            *(float4*)&Bs[br][bc] = *(const float4*)&W1[(size_t)(k0 + br) * HID_CH + bc];
        }
        __syncthreads();
#pragma unroll
        for (int kk = 0; kk < BK; kk++) {
            float4 av = *(const float4*)&Ast[kk][tr * 4];
            float2 bv0 = *(const float2*)&Bs[kk][tc * 2];
            float2 bv1 = *(const float2*)&Bs[kk][tc * 2 + 64];
            float2 bv2 = *(const float2*)&Bs[kk][tc * 2 + 128];
            float2 bv3 = *(const float2*)&Bs[kk][tc * 2 + 192];
            float a[4] = {av.x, av.y, av.z, av.w};
#pragma unroll
            for (int i = 0; i < 4; i++) {
                acc[i][0] = fmaf(a[i], bv0.x, acc[i][0]);
                acc[i][1] = fmaf(a[i], bv0.y, acc[i][1]);
                acc[i][2] = fmaf(a[i], bv1.x, acc[i][2]);
                acc[i][3] = fmaf(a[i], bv1.y, acc[i][3]);
                acc[i][4] = fmaf(a[i], bv2.x, acc[i][4]);
                acc[i][5] = fmaf(a[i], bv2.y, acc[i][5]);
                acc[i][6] = fmaf(a[i], bv3.x, acc[i][6]);
                acc[i][7] = fmaf(a[i], bv3.y, acc[i][7]);
            }
        }
        __syncthreads();
    }

    // bias + relu -> hid tile in LDS (float2 stores at addr 2*tc: 2-way, free)
#pragma unroll
    for (int j = 0; j < 4; j++) {
        float2 bb = *(const float2*)&b1[tc * 2 + 64 * j];
#pragma unroll
        for (int i = 0; i < 4; i++) {
            float2 v;
            v.x = fmaxf(acc[i][2 * j] + bb.x, 0.f);
            v.y = fmaxf(acc[i][2 * j + 1] + bb.y, 0.f);
            *(float2*)&hs[tr * 4 + i][tc * 2 + 64 * j] = v;
        }
    }
    __syncthreads();

    // GEMM2: 32x32 outputs; thread -> rows rg*4+[0..3], col o; W2 from global (L1)
    const int rg = tid >> 5, o = tid & 31;
    float o0 = 0.f, o1 = 0.f, o2 = 0.f, o3 = 0.f;
    for (int c = 0; c < HID_CH; c += 4) {
        float4 h0v = *(const float4*)&hs[rg * 4 + 0][c];
        float4 h1v = *(const float4*)&hs[rg * 4 + 1][c];
        float4 h2v = *(const float4*)&hs[rg * 4 + 2][c];
        float4 h3v = *(const float4*)&hs[rg * 4 + 3][c];
        float w0 = W2[(size_t)(c + 0) * OUT_CH + o];
        float w1 = W2[(size_t)(c + 1) * OUT_CH + o];
        float w2 = W2[(size_t)(c + 2) * OUT_CH + o];
        float w3 = W2[(size_t)(c + 3) * OUT_CH + o];
        o0 = fmaf(h0v.x, w0, fmaf(h0v.y, w1, fmaf(h0v.z, w2, fmaf(h0v.w, w3, o0))));
        o1 = fmaf(h1v.x, w0, fmaf(h1v.y, w1, fmaf(h1v.z, w2, fmaf(h1v.w, w3, o1))));
        o2 = fmaf(h2v.x, w0, fmaf(h2v.y, w1, fmaf(h2v.z, w2, fmaf(h2v.w, w3, o2))));
        o3 = fmaf(h3v.x, w0, fmaf(h3v.y, w1, fmaf(h3v.z, w2, fmaf(h3v.w, w3, o3))));
    }
    float bb = b2[o];
    float vals[4] = {o0, o1, o2, o3};
#pragma unroll
    for (int i = 0; i < 4; i++) {
        int r = row0 + rg * 4 + i;
        float v = vals[i] + bb;
        h0p[(size_t)r * OUT_CH + o] = v;
        g0p[(size_t)r * OUT_CH + o] = dinv[r] * v;
    }
}

// ---------------- propagation step (pull, no atomics) ----------------
// state iterated on g = dinv*h ; h materialized only on the final step.
// h' = alpha*h0 + (1-alpha)*dinv*(sum_{in-edges} g[src] + g[v]) ; g' = dinv*h'

__global__ __launch_bounds__(256) void prop_kernel(
    const float* __restrict__ g_in, const float* __restrict__ h0,
    const float* __restrict__ dinv, const int* __restrict__ row_ptr,
    const int* __restrict__ col, float* __restrict__ out, int final_step) {
    int v = blockIdx.x * 8 + threadIdx.y;
    if (v >= N_NODES) return;
    int c = threadIdx.x;
    int beg = row_ptr[v], end = row_ptr[v + 1];
    float acc = 0.f;
    int j = beg;
    for (; j + 3 < end; j += 4) {
        int s0 = col[j], s1 = col[j + 1], s2 = col[j + 2], s3 = col[j + 3];
        float a = g_in[(size_t)s0 * OUT_CH + c];
        float b = g_in[(size_t)s1 * OUT_CH + c];
        float d = g_in[(size_t)s2 * OUT_CH + c];
        float e = g_in[(size_t)s3 * OUT_CH + c];
        acc += (a + b) + (d + e);
    }
    for (; j < end; ++j) acc += g_in[(size_t)col[j] * OUT_CH + c];
    acc += g_in[(size_t)v * OUT_CH + c];  // self-loop: g[v]
    float dv = dinv[v];
    float h = ALPHA * h0[(size_t)v * OUT_CH + c] + (1.f - ALPHA) * dv * acc;
    out[(size_t)v * OUT_CH + c] = final_step ? h : dv * h;
}

// ---------------- launch ----------------

extern "C" void kernel_launch(void* const* d_in, const int* in_sizes, int n_in,
                              void* d_out, int out_size, void* d_ws, size_t ws_size,
                              hipStream_t stream) {
    const float* x = (const float*)d_in[0];
    const int* ei = (const int*)d_in[1];  // harness stages integers as int32
    const float* W1 = (const float*)d_in[2];
    const float* b1 = (const float*)d_in[3];
    const float* W2 = (const float*)d_in[4];
    const float* b2 = (const float*)d_in[5];
    float* out = (float*)d_out;
    const int E = in_sizes[1] / 2;

    char* ws = (char*)d_ws;
    size_t off = 0;
    auto alloc = [&](size_t bytes) -> void* {
        void* p = ws + off;
        off = (off + bytes + 255) & ~(size_t)255;
        return p;
    };
    int* cnt = (int*)alloc((size_t)N_NODES * 4);
    int* row_ptr = (int*)alloc((size_t)(N_NODES + 1) * 4);
    int* fill = (int*)alloc((size_t)N_NODES * 4);
    float* dinv = (float*)alloc((size_t)N_NODES * 4);
    int* sums = (int*)alloc(128 * 4);
    int* chunk_off = (int*)alloc(128 * 4);
    int* col = (int*)alloc((size_t)E * 4);
    float* h0 = (float*)alloc((size_t)N_NODES * OUT_CH * 4);
    float* g0 = (float*)alloc((size_t)N_NODES * OUT_CH * 4);
    float* gA = (float*)alloc((size_t)N_NODES * OUT_CH * 4);

    const int nchunks = (N_NODES + 1023) / 1024;  // 98

    zero_kernel<<<(N_NODES + 255) / 256, 256, 0, stream>>>(cnt, N_NODES);
    hist_kernel<<<(E + 255) / 256, 256, 0, stream>>>(ei, cnt, E);
    scan1_kernel<<<nchunks, 256, 0, stream>>>(cnt, row_ptr, sums, N_NODES);
    scan2_kernel<<<1, 128, 0, stream>>>(sums, chunk_off, nchunks);
    scan3_kernel<<<(N_NODES + 255) / 256, 256, 0, stream>>>(cnt, chunk_off, row_ptr, fill, dinv,
                                                            N_NODES, E);
    scatter_kernel<<<(E + 255) / 256, 256, 0, stream>>>(ei, fill, col, E);

    mlp_kernel<<<N_NODES / 32, 256, 0, stream>>>(x, W1, b1, W2, b2, dinv, h0, g0);

    dim3 pb(32, 8);
    int pg = (N_NODES + 7) / 8;
    const float* gin = g0;
    float* gout = gA;
    for (int s = 0; s < K_STEPS; s++) {
        int fin = (s == K_STEPS - 1);
        float* o = fin ? out : gout;
        prop_kernel<<<pg, pb, 0, stream>>>(gin, h0, dinv, row_ptr, col, o, fin);
        if (!fin) {
            float* t = (float*)gin;  // swap buffers
            gin = gout;
            gout = t;
        }
    }
}